// Round 10
// baseline (3196.107 us; speedup 1.0000x reference)
//
#include <hip/hip_runtime.h>

typedef _Float16 half8 __attribute__((ext_vector_type(8)));
typedef float floatx4 __attribute__((ext_vector_type(4)));
typedef unsigned long long u64t;

#define B_ 64
#define S_ 512
#define H_ 1024

// Launch epoch base in .bss (zero at load). Block 0 tid 0 bumps it by 1024
// (> S_+1) at kernel END -- provably after every block's start-read of it,
// since block0 finishing its scan requires every block's published data,
// which is published only after that block read tagctr. So all blocks of a
// launch agree on e0, and tags never repeat across launches (stride 1024).
// Poison (0xAAAAAAAA) / zeros never match an expected tag.
__device__ unsigned tagctr;

__device__ __forceinline__ float sigmoidf_(float x) { return 1.0f / (1.0f + __expf(-x)); }
__device__ __forceinline__ float tanhf_(float x) {
    return 1.0f - 2.0f / (__expf(2.0f * x) + 1.0f);   // saturates correctly via __expf
}

// 256 blocks x 256 threads (proven cooperative envelope). Block (cb=bid&63,
// mb=bid>>6) owns the 16x16 output tile: batches [16mb,16mb+16) x cols
// [16cb,16cb+16), FULL K=1024; wave = K-quarter; K-reduce in LDS
// (double-buffered -> ONE __syncthreads per step).
//
// NO barrier, NO slots, NO fences: tagged-payload dataflow (proven r9).
// Publication unit = 8 B agent-relaxed atomic word {tag32, 2x f16 xi}.
// r10 change: BATCH-POLL -- all 32 words a wave's step needs are loaded in
// one unrolled burst (pipelined behind ~1 LLC round-trip), tags checked
// together, retried on any miss (per-lane exit). r9 polled per-ks (8
// control-dependent bursts = 8 serialized round-trips -- the measured 5us
// critical path). MFMAs then consume captured registers.
__global__ void __launch_bounds__(256, 1)
lstm_scan(const float* __restrict__ emb, const float* __restrict__ W, const float* __restrict__ bW,
          const float* __restrict__ U, const float* __restrict__ bU,
          const float* __restrict__ V, const float* __restrict__ bV,
          float* __restrict__ out, unsigned char* __restrict__ ws)
{
    const int bid  = blockIdx.x;
    const int cb   = bid & 63;    // column group (16 H-cols)
    const int mb   = bid >> 6;    // batch group (16 batches)
    const int tid  = threadIdx.x;
    const int w    = tid >> 6;    // wave id = K-quarter
    const int lane = tid & 63;
    const int fr   = lane & 15;   // frag row index (A row within tile)
    const int kg   = lane >> 4;   // frag k-block

    u64t* pub = (u64t*)ws;        // [2][64 rows][512 pairs] u64 = 512 KB

    __shared__ __align__(16) float part[2][4 * 3 * 64 * 4];   // 2 x 12 KB

    const unsigned e0 = __hip_atomic_load(&tagctr, __ATOMIC_RELAXED,
                                          __HIP_MEMORY_SCOPE_AGENT);

    // ---- persistent weight fragments (f16, registers): 3 gates x 8 ksteps ----
    // B-frag of mfma_f32_16x16x32_f16: lane l holds B[k=(l>>4)*8+e][n=l&15],
    // B[k][n] = Wgate[16*cb + n][k].  (Layout proven rounds 1/4/5/6/7/8/9.)
    half8 Bf[3][8];
    {
        const int jrow = cb * 16 + fr;
        const int kb   = w * 256 + kg * 8;
        const float* p0 = W + jrow * H_ + kb;
        const float* p1 = U + jrow * H_ + kb;
        const float* p2 = V + jrow * H_ + kb;
        #pragma unroll
        for (int ks = 0; ks < 8; ++ks) {
            half8 h0, h1, h2;
            #pragma unroll
            for (int e = 0; e < 8; ++e) {
                h0[e] = (_Float16)p0[ks * 32 + e];
                h1[e] = (_Float16)p1[ks * 32 + e];
                h2[e] = (_Float16)p2[ks * 32 + e];
            }
            Bf[0][ks] = h0; Bf[1][ks] = h1; Bf[2][ks] = h2;
        }
    }

    // ---- elementwise ownership: thread -> ONE cell (b, j) ----
    const int rt = tid >> 4;
    const int ct = tid & 15;
    const int b  = mb * 16 + rt;
    const int j  = cb * 16 + ct;
    const float bw = bW[j], bu = bU[j], bv = bV[j];
    const int rl = (rt >> 2) * 16 + ct;   // C/D source lane (proven)
    const int rr = rt & 3;                // C/D source reg
    const bool evenct = (ct & 1) == 0;
    const unsigned widx = (unsigned)(b * 512 + cb * 8 + (ct >> 1));  // pair slot

    // publish own xi value (paired with ct^1 neighbor) as one tagged 8B word.
    auto publish = [&](int buf, unsigned tag, float xin) {
        union { _Float16 h; unsigned short u; } cv;
        cv.h = (_Float16)xin;
        unsigned mine  = cv.u;
        unsigned other = (unsigned)__shfl_xor((int)mine, 1);
        if (evenct)
            __hip_atomic_store(&pub[(unsigned)buf * (64 * 512) + widx],
                               ((u64t)tag << 32) | (u64t)(mine | (other << 16)),
                               __ATOMIC_RELAXED, __HIP_MEMORY_SCOPE_AGENT);
    };

    float p1s = 0.0f;
    float xio = emb[(b * S_ + 0) * H_ + j];    // p2 init = 0
    publish(0, e0 + 1u, xio);
    float embn = emb[(b * S_ + 1) * H_ + j];   // prefetch t=1

    for (int t = 0; t < S_; ++t) {
        const u64t* rowp = pub + (unsigned)(t & 1) * (64 * 512)
                               + (unsigned)(mb * 16 + fr) * 512;
        const unsigned tag   = e0 + (unsigned)t + 1u;
        const unsigned pbase = (unsigned)(w * 128 + kg * 4);

        // ---- BATCH poll: all 32 words in one burst (1 round-trip) ----
        u64t q[32];
        for (;;) {
            #pragma unroll
            for (int i = 0; i < 32; ++i)
                q[i] = __hip_atomic_load(
                    &rowp[pbase + (unsigned)(((i >> 2) * 16) + (i & 3))],
                    __ATOMIC_RELAXED, __HIP_MEMORY_SCOPE_AGENT);
            bool ok = true;
            #pragma unroll
            for (int i = 0; i < 32; ++i)
                ok = ok && ((unsigned)(q[i] >> 32) == tag);
            if (ok) break;
            __builtin_amdgcn_s_sleep(1);
        }

        // ---- MFMA from captured registers ----
        floatx4 a0 = {0.f, 0.f, 0.f, 0.f};
        floatx4 a1 = {0.f, 0.f, 0.f, 0.f};
        floatx4 a2 = {0.f, 0.f, 0.f, 0.f};
        #pragma unroll
        for (int ks = 0; ks < 8; ++ks) {
            union { unsigned u[4]; half8 h; } cv;
            cv.u[0] = (unsigned)q[ks * 4 + 0];
            cv.u[1] = (unsigned)q[ks * 4 + 1];
            cv.u[2] = (unsigned)q[ks * 4 + 2];
            cv.u[3] = (unsigned)q[ks * 4 + 3];
            a0 = __builtin_amdgcn_mfma_f32_16x16x32_f16(cv.h, Bf[0][ks], a0, 0, 0, 0);
            a1 = __builtin_amdgcn_mfma_f32_16x16x32_f16(cv.h, Bf[1][ks], a1, 0, 0, 0);
            a2 = __builtin_amdgcn_mfma_f32_16x16x32_f16(cv.h, Bf[2][ks], a2, 0, 0, 0);
        }

        // ---- K-reduction in LDS (double-buffered -> one sync per step) ----
        float* pp = part[t & 1];
        *(floatx4*)&pp[((w * 3 + 0) * 64 + lane) * 4] = a0;
        *(floatx4*)&pp[((w * 3 + 1) * 64 + lane) * 4] = a1;
        *(floatx4*)&pp[((w * 3 + 2) * 64 + lane) * 4] = a2;
        __syncthreads();

        float pf = bw, pu = bu, pv = bv;
        #pragma unroll
        for (int wv = 0; wv < 4; ++wv) {
            pf += pp[((wv * 3 + 0) * 64 + rl) * 4 + rr];
            pu += pp[((wv * 3 + 1) * 64 + rl) * 4 + rr];
            pv += pp[((wv * 3 + 2) * 64 + rl) * 4 + rr];
        }

        // ---- gates + state update ----
        float fg = sigmoidf_(pf);
        float ig = sigmoidf_(pu);
        float gg = tanhf_(pv);
        p1s = fg * p1s + ig * gg;
        float p2 = sigmoidf_(xio) * tanhf_(p1s);

        if (t < S_ - 1) {
            float xin = embn + p2;
            xio = xin;
            publish((t + 1) & 1, e0 + (unsigned)t + 2u, xin);   // fire and forget
            __builtin_nontemporal_store(p2, &out[(b * S_ + t) * H_ + j]);
            if (t + 2 < S_) embn = emb[(b * S_ + t + 2) * H_ + j];
        } else {
            __builtin_nontemporal_store(p2, &out[(b * S_ + t) * H_ + j]);
        }
    }

    // bump epoch base for the next launch (after all communication done)
    if (bid == 0 && tid == 0)
        __hip_atomic_store(&tagctr, e0 + 1024u, __ATOMIC_RELAXED,
                           __HIP_MEMORY_SCOPE_AGENT);
}

extern "C" void kernel_launch(void* const* d_in, const int* in_sizes, int n_in,
                              void* d_out, int out_size, void* d_ws, size_t ws_size,
                              hipStream_t stream)
{
    const float* emb = (const float*)d_in[0];
    const float* W   = (const float*)d_in[1];
    const float* bWv = (const float*)d_in[2];
    const float* U   = (const float*)d_in[3];
    const float* bUv = (const float*)d_in[4];
    const float* V   = (const float*)d_in[5];
    const float* bVv = (const float*)d_in[6];
    float* outp = (float*)d_out;
    unsigned char* ws = (unsigned char*)d_ws;
    (void)in_sizes; (void)n_in; (void)out_size; (void)ws_size;

    void* args[] = {(void*)&emb, (void*)&W, (void*)&bWv, (void*)&U, (void*)&bUv,
                    (void*)&V, (void*)&bVv, (void*)&outp, (void*)&ws};
    hipLaunchCooperativeKernel((const void*)lstm_scan, dim3(256), dim3(256),
                               args, 0, stream);
}

// Round 11
// 2219.619 us; speedup vs baseline: 1.4399x; 1.4399x over previous
//
#include <hip/hip_runtime.h>

typedef _Float16 half8 __attribute__((ext_vector_type(8)));
typedef float floatx4 __attribute__((ext_vector_type(4)));
typedef unsigned int uintx4 __attribute__((ext_vector_type(4)));
typedef unsigned long long u64t;

#define B_ 64
#define S_ 512
#define H_ 1024

// Epoch base + slots in .bss (zero at load; never touched by ws poison).
// Monotonic: slots advance by exactly S_ per launch (init publish e0+1,
// then e0+t+2 up to e0+S_); tagctr advances by 1024 > S_ per launch, bumped
// by block 0 at kernel END (provably after every block read it: block0 can
// finish only after observing every block's slots, which are stored only
// after that block's start-read of tagctr). Stale slot values from launch
// N-1 (<= e0_prev + S_) can never satisfy launch N's targets (>= e0 + 1).
__device__ unsigned slotA[4][64];
__device__ unsigned tagctr;

__device__ __forceinline__ float sigmoidf_(float x) { return 1.0f / (1.0f + __expf(-x)); }
__device__ __forceinline__ float tanhf_(float x) {
    return 1.0f - 2.0f / (__expf(2.0f * x) + 1.0f);   // saturates correctly via __expf
}

// 256 blocks x 256 threads (proven cooperative envelope). Block (cb=bid&63,
// mb=bid>>6) owns the 16x16 output tile: batches [16mb,16mb+16) x cols
// [16cb,16cb+16), FULL K=1024; wave = K-quarter; K-reduce in LDS
// (double-buffered -> ONE __syncthreads per step).
//
// r11 protocol: UNTAGGED packed payload (4x f16 per 8B sc1 word -> half the
// fabric broadcast of r9/r10) + per-wave slot handshake (publisher: payload
// sc1 stores -> vmcnt(0) drain -> syncthreads -> tid0 slot store; consumer
// wave polls ONLY its 16 source publishers' slots, 1 load/lane/retry).
// Payload read = 8 forced inline-asm global_load_dwordx4 sc1 (compiler
// cannot serialize them -> true single-round-trip burst; r10's failure was
// the compiler chunking the burst to fit 116 VGPRs).
__global__ void __launch_bounds__(256, 1)
lstm_scan(const float* __restrict__ emb, const float* __restrict__ W, const float* __restrict__ bW,
          const float* __restrict__ U, const float* __restrict__ bU,
          const float* __restrict__ V, const float* __restrict__ bV,
          float* __restrict__ out, unsigned char* __restrict__ ws)
{
    const int bid  = blockIdx.x;
    const int cb   = bid & 63;    // column group (16 H-cols)
    const int mb   = bid >> 6;    // batch group (16 batches)
    const int tid  = threadIdx.x;
    const int w    = tid >> 6;    // wave id = K-quarter
    const int lane = tid & 63;
    const int fr   = lane & 15;   // frag row index (A row within tile)
    const int kg   = lane >> 4;   // frag k-block

    u64t* pub = (u64t*)ws;        // [2][64 rows][256 words] u64, 4 f16/word = 256 KB

    __shared__ __align__(16) float part[2][4 * 3 * 64 * 4];   // 2 x 12 KB

    const unsigned e0 = __hip_atomic_load(&tagctr, __ATOMIC_RELAXED,
                                          __HIP_MEMORY_SCOPE_AGENT);

    // ---- persistent weight fragments (f16, registers): 3 gates x 8 ksteps ----
    // B-frag of mfma_f32_16x16x32_f16: lane l holds B[k=(l>>4)*8+e][n=l&15],
    // B[k][n] = Wgate[16*cb + n][k].  (Layout proven rounds 1/4-10.)
    half8 Bf[3][8];
    {
        const int jrow = cb * 16 + fr;
        const int kb   = w * 256 + kg * 8;
        const float* p0 = W + jrow * H_ + kb;
        const float* p1 = U + jrow * H_ + kb;
        const float* p2 = V + jrow * H_ + kb;
        #pragma unroll
        for (int ks = 0; ks < 8; ++ks) {
            half8 h0, h1, h2;
            #pragma unroll
            for (int e = 0; e < 8; ++e) {
                h0[e] = (_Float16)p0[ks * 32 + e];
                h1[e] = (_Float16)p1[ks * 32 + e];
                h2[e] = (_Float16)p2[ks * 32 + e];
            }
            Bf[0][ks] = h0; Bf[1][ks] = h1; Bf[2][ks] = h2;
        }
    }

    // ---- elementwise ownership: thread -> ONE cell (b, j) ----
    const int rt = tid >> 4;
    const int ct = tid & 15;
    const int b  = mb * 16 + rt;
    const int j  = cb * 16 + ct;
    const float bw = bW[j], bu = bU[j], bv = bV[j];
    const int rl = (rt >> 2) * 16 + ct;   // C/D source lane (proven)
    const int rr = rt & 3;                // C/D source reg

    // publish: pack 4 f16 (lanes ct&~3 .. +3) into one 8B sc1 word, drain,
    // then tid0 raises this block's slot. (r8-proven ordering mechanism.)
    auto publish = [&](int buf, unsigned slotval, float xin) {
        union { _Float16 h; unsigned short u; } cv;
        cv.h = (_Float16)xin;
        unsigned mine = cv.u;
        unsigned lo = mine | ((unsigned)__shfl_xor((int)mine, 1) << 16); // f16[ct]|f16[ct+1]
        unsigned hi = (unsigned)__shfl_xor((int)lo, 2);                  // f16[ct+2]|f16[ct+3]
        if ((ct & 3) == 0)
            __hip_atomic_store(&pub[(unsigned)(buf * 16384 + b * 256 + cb * 4 + (ct >> 2))],
                               (u64t)lo | ((u64t)hi << 32),
                               __ATOMIC_RELAXED, __HIP_MEMORY_SCOPE_AGENT);
        asm volatile("s_waitcnt vmcnt(0)" ::: "memory");  // payload acked at LLC
        __syncthreads();
        if (tid == 0)
            __hip_atomic_store(&slotA[mb][cb], slotval, __ATOMIC_RELAXED,
                               __HIP_MEMORY_SCOPE_AGENT);
    };

    // per-wave wait: wave w consumes only publishers cb' in [16w,16w+16);
    // lane polls slot[16w + (lane&15)] (4x replicated), one load per retry.
    auto waitsrc = [&](unsigned tgt) {
        const int sidx = w * 16 + (lane & 15);
        for (;;) {
            unsigned v = __hip_atomic_load(&slotA[mb][sidx], __ATOMIC_RELAXED,
                                           __HIP_MEMORY_SCOPE_AGENT);
            if (__all((int)(v - tgt) >= 0)) break;
            __builtin_amdgcn_s_sleep(1);
        }
        asm volatile("" ::: "memory");
    };

    float p1s = 0.0f;
    float xio = emb[(b * S_ + 0) * H_ + j];    // p2 init = 0
    publish(0, e0 + 1u, xio);
    float embn = emb[(b * S_ + 1) * H_ + j];   // prefetch t=1

    for (int t = 0; t < S_; ++t) {
        waitsrc(e0 + (unsigned)t + 1u);

        // ---- payload burst: 8 forced dwordx4 sc1 loads (one round-trip) ----
        // lane needs k = w*256 + ks*32 + kg*8 + [0,8) for ks=0..7
        //          = u64 words  w*64 + ks*8 + kg*2 + {0,1}  (16B per ks)
        const u64t* rowbase = pub + (unsigned)((t & 1) * 16384
                               + (mb * 16 + fr) * 256 + w * 64 + kg * 2);
        uintx4 ld0, ld1, ld2, ld3, ld4, ld5, ld6, ld7;
        asm volatile("global_load_dwordx4 %0, %1, off sc1"             : "=v"(ld0) : "v"(rowbase));
        asm volatile("global_load_dwordx4 %0, %1, off offset:64 sc1"   : "=v"(ld1) : "v"(rowbase));
        asm volatile("global_load_dwordx4 %0, %1, off offset:128 sc1"  : "=v"(ld2) : "v"(rowbase));
        asm volatile("global_load_dwordx4 %0, %1, off offset:192 sc1"  : "=v"(ld3) : "v"(rowbase));
        asm volatile("global_load_dwordx4 %0, %1, off offset:256 sc1"  : "=v"(ld4) : "v"(rowbase));
        asm volatile("global_load_dwordx4 %0, %1, off offset:320 sc1"  : "=v"(ld5) : "v"(rowbase));
        asm volatile("global_load_dwordx4 %0, %1, off offset:384 sc1"  : "=v"(ld6) : "v"(rowbase));
        asm volatile("global_load_dwordx4 %0, %1, off offset:448 sc1"  : "=v"(ld7) : "v"(rowbase));
        asm volatile("s_waitcnt vmcnt(0)" ::: "memory");
        __builtin_amdgcn_sched_barrier(0);     // rule #18: pin MFMAs after the wait

        // ---- MFMA from captured registers ----
        floatx4 a0 = {0.f, 0.f, 0.f, 0.f};
        floatx4 a1 = {0.f, 0.f, 0.f, 0.f};
        floatx4 a2 = {0.f, 0.f, 0.f, 0.f};
        union { uintx4 v; half8 h; } cv;
        uintx4 lds_[8] = {ld0, ld1, ld2, ld3, ld4, ld5, ld6, ld7};
        #pragma unroll
        for (int ks = 0; ks < 8; ++ks) {
            cv.v = lds_[ks];
            a0 = __builtin_amdgcn_mfma_f32_16x16x32_f16(cv.h, Bf[0][ks], a0, 0, 0, 0);
            a1 = __builtin_amdgcn_mfma_f32_16x16x32_f16(cv.h, Bf[1][ks], a1, 0, 0, 0);
            a2 = __builtin_amdgcn_mfma_f32_16x16x32_f16(cv.h, Bf[2][ks], a2, 0, 0, 0);
        }

        // ---- K-reduction in LDS (double-buffered -> one sync per step) ----
        float* pp = part[t & 1];
        *(floatx4*)&pp[((w * 3 + 0) * 64 + lane) * 4] = a0;
        *(floatx4*)&pp[((w * 3 + 1) * 64 + lane) * 4] = a1;
        *(floatx4*)&pp[((w * 3 + 2) * 64 + lane) * 4] = a2;
        __syncthreads();

        float pf = bw, pu = bu, pv = bv;
        #pragma unroll
        for (int wv = 0; wv < 4; ++wv) {
            pf += pp[((wv * 3 + 0) * 64 + rl) * 4 + rr];
            pu += pp[((wv * 3 + 1) * 64 + rl) * 4 + rr];
            pv += pp[((wv * 3 + 2) * 64 + rl) * 4 + rr];
        }

        // ---- gates + state update ----
        float fg = sigmoidf_(pf);
        float ig = sigmoidf_(pu);
        float gg = tanhf_(pv);
        p1s = fg * p1s + ig * gg;
        float p2 = sigmoidf_(xio) * tanhf_(p1s);

        if (t < S_ - 1) {
            float xin = embn + p2;
            xio = xin;
            publish((t + 1) & 1, e0 + (unsigned)t + 2u, xin);
            // after the slot store: drain during other blocks' polls
            __builtin_nontemporal_store(p2, &out[(b * S_ + t) * H_ + j]);
            if (t + 2 < S_) embn = emb[(b * S_ + t + 2) * H_ + j];
        } else {
            __builtin_nontemporal_store(p2, &out[(b * S_ + t) * H_ + j]);
        }
    }

    // bump epoch base for the next launch (after all communication done)
    if (bid == 0 && tid == 0)
        __hip_atomic_store(&tagctr, e0 + 1024u, __ATOMIC_RELAXED,
                           __HIP_MEMORY_SCOPE_AGENT);
}

extern "C" void kernel_launch(void* const* d_in, const int* in_sizes, int n_in,
                              void* d_out, int out_size, void* d_ws, size_t ws_size,
                              hipStream_t stream)
{
    const float* emb = (const float*)d_in[0];
    const float* W   = (const float*)d_in[1];
    const float* bWv = (const float*)d_in[2];
    const float* U   = (const float*)d_in[3];
    const float* bUv = (const float*)d_in[4];
    const float* V   = (const float*)d_in[5];
    const float* bVv = (const float*)d_in[6];
    float* outp = (float*)d_out;
    unsigned char* ws = (unsigned char*)d_ws;
    (void)in_sizes; (void)n_in; (void)out_size; (void)ws_size;

    void* args[] = {(void*)&emb, (void*)&W, (void*)&bWv, (void*)&U, (void*)&bUv,
                    (void*)&V, (void*)&bVv, (void*)&outp, (void*)&ws};
    hipLaunchCooperativeKernel((const void*)lstm_scan, dim3(256), dim3(256),
                               args, 0, stream);
}